// Round 10
// baseline (104.622 us; speedup 1.0000x reference)
//
#include <hip/hip_runtime.h>
#include <math.h>

// SS2D: B=1, D=96, H=W=96, L=9216, K=4, N=16, R=6
constexpr int cD = 96, cL = 9216, cK = 4;
constexpr int CL = 72, NCH = 128;       // 128 chunks of 72 per sequence
constexpr float LOG2E = 1.44269504088896f;

// ws float offsets (~36.6 MB)
constexpr long OFF_XT    = 0;                       // [96][9216]
constexpr long OFF_DELTA = OFF_XT    + (long)cD*cL; // [K][96][9216] d-major
constexpr long OFF_BS    = OFF_DELTA + 4L*cD*cL;    // [K][72][128][16] j-major
constexpr long OFF_CS    = OFF_BS    + 4L*cL*16;    // [K][72][128][16]
constexpr long OFF_Y     = OFF_CS    + 4L*cL*16;    // [K][96][9216] d-major raster

__device__ __forceinline__ float4 a2prep(float4 v) {
    return make_float4(-LOG2E * exp2f(LOG2E * v.x), -LOG2E * exp2f(LOG2E * v.y),
                       -LOG2E * exp2f(LOG2E * v.z), -LOG2E * exp2f(LOG2E * v.w));
}

// ---- kT: xT[d][w*96+h] = x[d][h*96+w] --------------------------------------
__global__ __launch_bounds__(256) void kT(const float* __restrict__ x,
                                          float* __restrict__ xT) {
    __shared__ float t[32][33];
    const int h0 = blockIdx.x * 32, w0 = blockIdx.y * 32, d = blockIdx.z;
    const float* xd = x + (long)d * cL;
    float* xtd = xT + (long)d * cL;
    for (int o = threadIdx.x; o < 1024; o += 256) {
        int i = o >> 5, j = o & 31;
        t[i][j] = xd[(h0 + i) * 96 + w0 + j];
    }
    __syncthreads();
    for (int o = threadIdx.x; o < 1024; o += 256) {
        int i = o >> 5, j = o & 31;
        xtd[(w0 + i) * 96 + h0 + j] = t[j][i];
    }
}

// ---- kA: G = W_k @ src_k; delta[k][d][p], Bs/Cs[k][72][128][16] ------------
__global__ __launch_bounds__(256) void kA(const float* __restrict__ x,
                                          const float* __restrict__ xT,
                                          const float* __restrict__ xpw,
                                          const float* __restrict__ dtw,
                                          const float* __restrict__ dtb,
                                          float* __restrict__ delta,
                                          float* __restrict__ Bs,
                                          float* __restrict__ Cs) {
    __shared__ float xs[96][64];
    __shared__ float xdbl[38][65];
    __shared__ float dtw_l[96 * 6];
    __shared__ float dtb_l[96];
    const int p0 = blockIdx.x * 64;
    const int k  = blockIdx.y;
    const int tid = threadIdx.x;
    const float* src = (k & 1) ? xT : x;

    for (int o = tid; o < 96 * 64; o += 256) {
        int dd = o >> 6, pp = o & 63;
        xs[dd][pp] = src[(long)dd * cL + p0 + pp];
    }
    for (int o = tid; o < 96 * 6; o += 256) dtw_l[o] = dtw[k * 96 * 6 + o];
    if (tid < 96) dtb_l[tid] = dtb[k * 96 + tid];
    __syncthreads();

    const int lane = tid & 63;
    const int c0 = __builtin_amdgcn_readfirstlane((tid >> 6) * 10);
    const float* wk = xpw + (long)k * 38 * 96;
    float acc[10];
    #pragma unroll
    for (int i = 0; i < 10; ++i) acc[i] = 0.f;
    #pragma unroll 4
    for (int dd = 0; dd < 96; ++dd) {
        float xv = xs[dd][lane];
        #pragma unroll
        for (int i = 0; i < 10; ++i) {
            int c = c0 + i; c = c > 37 ? 37 : c;
            acc[i] = fmaf(xv, wk[c * 96 + dd], acc[i]);
        }
    }
    #pragma unroll
    for (int i = 0; i < 10; ++i) {
        int c = c0 + i; c = c > 37 ? 37 : c;
        xdbl[c][lane] = acc[i];
    }
    __syncthreads();

    // Bs/Cs scan-chunk-major: q = scan index, ch = q/72, j = q%72
    for (int o = tid; o < 64 * 16; o += 256) {
        int n = o & 15, pp = o >> 4;
        int P = p0 + pp;
        int q = (k < 2) ? P : (9215 - P);
        int ch = q / 72, j = q - ch * 72;
        long idx = (((long)k * 72 + j) * 128 + ch) * 16 + n;
        Bs[idx] = xdbl[6 + n][pp];
        Cs[idx] = xdbl[22 + n][pp];
    }
    for (int o = tid; o < 96 * 64; o += 256) {
        int dd = o >> 6, pp = o & 63;
        float s = dtb_l[dd];
        #pragma unroll
        for (int r = 0; r < 6; ++r) s = fmaf(xdbl[r][pp], dtw_l[dd * 6 + r], s);
        float sp = fmaxf(s, 0.f) + __logf(1.f + __expf(-fabsf(s)));
        delta[((long)(k * 96 + dd)) * cL + p0 + pp] = sp;
    }
}

// ---- kS: fused two-pass scan, one block per (k,d) sequence -----------------
// 512 thr = 128 quads; quad = chunk of 72; 4 n per lane.
__global__ __launch_bounds__(512, 4) void kS(const float* __restrict__ x,
                                             const float* __restrict__ xT,
                                             const float* __restrict__ delta,
                                             const float* __restrict__ Bs,
                                             const float* __restrict__ Cs,
                                             const float* __restrict__ Alog,
                                             const float* __restrict__ Dsv,
                                             float* __restrict__ y) {
    __shared__ float lp[NCH][16];        // 8 KB (rows 0..63 reused as gpf)
    __shared__ float ls[NCH][16];        // 8 KB
    __shared__ float ybuf[9216 + 96];    // 37.25 KB
    float* gpf = &lp[0][0];
    const int tid = threadIdx.x;
    const int seq = blockIdx.x;                    // k*96+d
    const int k = seq / 96, d = seq % 96, rev = k >> 1;
    const int n0 = (tid & 3) * 4, ch = tid >> 2;   // ch in [0,128)
    const int q0 = rev ? (9215 - ch * CL) : ch * CL;

    const float4 a2 = a2prep(*(const float4*)(Alog + (long)seq * 16 + n0));
    const float Dv = Dsv[seq];
    const float* dB = delta + (long)seq * cL + q0;
    const float* xB = ((k & 1) ? xT : x) + (long)d * cL + q0;
    const float* bB = Bs + (long)k * cL * 16 + (long)ch * 16 + n0;
    const float* cB = Cs + (long)k * cL * 16 + (long)ch * 16 + n0;

    // ---- pass 1: chunk summary ----
    float4 h = make_float4(0.f, 0.f, 0.f, 0.f);
    float sdl = 0.f;
#define S1(DL, XV, OFF) { \
        float4 B = *(const float4*)(bB + (OFF) * 2048); \
        float t = (DL) * (XV); sdl += (DL); \
        h.x = fmaf(exp2f((DL)*a2.x), h.x, t*B.x); \
        h.y = fmaf(exp2f((DL)*a2.y), h.y, t*B.y); \
        h.z = fmaf(exp2f((DL)*a2.z), h.z, t*B.z); \
        h.w = fmaf(exp2f((DL)*a2.w), h.w, t*B.w); }
    if (!rev) {
        #pragma unroll
        for (int g = 0; g < 18; ++g) {
            float4 d4 = *(const float4*)(dB + 4*g);
            float4 x4 = *(const float4*)(xB + 4*g);
            S1(d4.x, x4.x, 4*g)   S1(d4.y, x4.y, 4*g+1)
            S1(d4.z, x4.z, 4*g+2) S1(d4.w, x4.w, 4*g+3)
        }
    } else {
        #pragma unroll
        for (int g = 0; g < 18; ++g) {
            float4 d4 = *(const float4*)(dB - 4*g - 3);
            float4 x4 = *(const float4*)(xB - 4*g - 3);
            S1(d4.w, x4.w, 4*g)   S1(d4.z, x4.z, 4*g+1)
            S1(d4.y, x4.y, 4*g+2) S1(d4.x, x4.x, 4*g+3)
        }
    }
#undef S1
    *(float4*)&lp[ch][n0] = make_float4(exp2f(a2.x*sdl), exp2f(a2.y*sdl),
                                        exp2f(a2.z*sdl), exp2f(a2.w*sdl));
    *(float4*)&ls[ch][n0] = h;
    __syncthreads();

    // ---- scan of 128 summaries: serial-4 -> KS over 32 groups -> apply ----
    const int sn = tid & 15, sg = tid >> 4;        // sg in [0,32)
    float LPe[4], LSe[4];
    {
        float P = 1.f, S = 0.f;
        #pragma unroll
        for (int i = 0; i < 4; ++i) {
            LPe[i] = P; LSe[i] = S;
            float p = lp[sg * 4 + i][sn], s = ls[sg * 4 + i][sn];
            S = fmaf(p, S, s); P = p * P;
        }
        __syncthreads();                           // phase-A reads done
        gpf[tid] = P; gpf[512 + tid] = S;          // overwrites lp rows 0..63
    }
    __syncthreads();
    #pragma unroll
    for (int off = 1; off < 32; off <<= 1) {
        float pc = gpf[tid], sc = gpf[512 + tid];
        float pn = pc, snn = sc;
        if (sg >= off) {
            pn  = pc * gpf[tid - off * 16];
            snn = fmaf(pc, gpf[512 + tid - off * 16], sc);
        }
        __syncthreads();
        gpf[tid] = pn; gpf[512 + tid] = snn;
        __syncthreads();
    }
    const float GS = (sg == 0) ? 0.f : gpf[512 + tid - 16];
    #pragma unroll
    for (int i = 0; i < 4; ++i) ls[sg * 4 + i][sn] = fmaf(LPe[i], GS, LSe[i]);
    __syncthreads();

    // ---- pass 2: replay with exclusive init ----
    h = *(float4*)&ls[ch][n0];
    const int slB = ch * CL;
    const bool lane0 = (tid & 3) == 0;
#define S2(DL, XV, OFF) { \
        float4 B = *(const float4*)(bB + (OFF) * 2048); \
        float4 C = *(const float4*)(cB + (OFF) * 2048); \
        float t = (DL) * (XV); \
        h.x = fmaf(exp2f((DL)*a2.x), h.x, t*B.x); \
        h.y = fmaf(exp2f((DL)*a2.y), h.y, t*B.y); \
        h.z = fmaf(exp2f((DL)*a2.z), h.z, t*B.z); \
        h.w = fmaf(exp2f((DL)*a2.w), h.w, t*B.w); \
        float pv = fmaf(h.x, C.x, fmaf(h.y, C.y, fmaf(h.z, C.z, h.w * C.w))); \
        pv += __shfl_xor(pv, 1, 4); \
        pv += __shfl_xor(pv, 2, 4); \
        if (lane0) { int sl = slB + (OFF); int yloc = rev ? 9215 - sl : sl; \
                     ybuf[yloc + yloc / 96] = fmaf(Dv, (XV), pv); } }
    if (!rev) {
        #pragma unroll
        for (int g = 0; g < 18; ++g) {
            float4 d4 = *(const float4*)(dB + 4*g);
            float4 x4 = *(const float4*)(xB + 4*g);
            S2(d4.x, x4.x, 4*g)   S2(d4.y, x4.y, 4*g+1)
            S2(d4.z, x4.z, 4*g+2) S2(d4.w, x4.w, 4*g+3)
        }
    } else {
        #pragma unroll
        for (int g = 0; g < 18; ++g) {
            float4 d4 = *(const float4*)(dB - 4*g - 3);
            float4 x4 = *(const float4*)(xB - 4*g - 3);
            S2(d4.w, x4.w, 4*g)   S2(d4.z, x4.z, 4*g+1)
            S2(d4.y, x4.y, 4*g+2) S2(d4.x, x4.x, 4*g+3)
        }
    }
#undef S2
    __syncthreads();

    // ---- writeout: ybuf (direction raster + pad) -> y[seq] raster ----
    float* yrow = y + (long)seq * cL;
    if (k & 1) {
        for (int o = tid; o < 9216; o += 512) {
            int hh = o / 96, wl = o - hh * 96;      // out p = hh*96+wl
            yrow[o] = ybuf[wl * 97 + hh];           // scan q = wl*96+hh
        }
    } else {
        for (int o = tid; o < 9216; o += 512) {
            yrow[o] = ybuf[o + o / 96];
        }
    }
}

// ---- kE: 4-dir sum (all raster, d-major) + LayerNorm; 32 p per block -------
__global__ __launch_bounds__(256) void kE(const float* __restrict__ y,
                                          const float* __restrict__ lnw,
                                          const float* __restrict__ lnb,
                                          float* __restrict__ out) {
    __shared__ float vs[96][36];
    __shared__ float red[8][32], red2[8][32];
    __shared__ float MU[32], RS[32];
    const int tid = threadIdx.x;
    const int p0 = blockIdx.x * 32;

    for (int o = tid; o < 96 * 8; o += 256) {
        int dd = o >> 3, j = o & 7;
        const float* r0 = y + (long)dd * cL + p0;
        const float* r1 = y + (long)(96 + dd) * cL + p0;
        const float* r2 = y + (long)(192 + dd) * cL + p0;
        const float* r3 = y + (long)(288 + dd) * cL + p0;
        float4 a = ((const float4*)r0)[j];
        float4 b = ((const float4*)r1)[j];
        float4 c = ((const float4*)r2)[j];
        float4 e = ((const float4*)r3)[j];
        *(float4*)&vs[dd][4 * j] = make_float4(a.x + b.x + c.x + e.x,
                                               a.y + b.y + c.y + e.y,
                                               a.z + b.z + c.z + e.z,
                                               a.w + b.w + c.w + e.w);
    }
    __syncthreads();

    const int p = tid & 31, part = tid >> 5;
    float s = 0.f, s2 = 0.f;
    for (int dd = part * 12; dd < part * 12 + 12; ++dd) {
        float v = vs[dd][p];
        s += v; s2 = fmaf(v, v, s2);
    }
    red[part][p] = s; red2[part][p] = s2;
    __syncthreads();
    if (tid < 32) {
        float S = 0.f, S2 = 0.f;
        #pragma unroll
        for (int q = 0; q < 8; ++q) { S += red[q][tid]; S2 += red2[q][tid]; }
        float m = S * (1.f / 96.f);
        MU[tid] = m;
        RS[tid] = rsqrtf(S2 * (1.f / 96.f) - m * m + 1e-5f);
    }
    __syncthreads();
    for (int o = tid; o < 32 * 96; o += 256) {
        int pl = o / 96, dd = o - pl * 96;
        out[(long)(p0 + pl) * 96 + dd] = (vs[dd][pl] - MU[pl]) * RS[pl] * lnw[dd] + lnb[dd];
    }
}

extern "C" void kernel_launch(void* const* d_in, const int* in_sizes, int n_in,
                              void* d_out, int out_size, void* d_ws, size_t ws_size,
                              hipStream_t stream) {
    const float* x    = (const float*)d_in[0];
    const float* xpw  = (const float*)d_in[1];
    const float* dtw  = (const float*)d_in[2];
    const float* dtb  = (const float*)d_in[3];
    const float* Alog = (const float*)d_in[4];
    const float* Dsv  = (const float*)d_in[5];
    const float* lnw  = (const float*)d_in[6];
    const float* lnb  = (const float*)d_in[7];
    float* ws = (float*)d_ws;

    float* xT    = ws + OFF_XT;
    float* delta = ws + OFF_DELTA;
    float* Bs    = ws + OFF_BS;
    float* Cs    = ws + OFF_CS;
    float* y     = ws + OFF_Y;
    float* out   = (float*)d_out;

    kT<<<dim3(3, 3, 96), 256, 0, stream>>>(x, xT);
    kA<<<dim3(144, 4), 256, 0, stream>>>(x, xT, xpw, dtw, dtb, delta, Bs, Cs);
    kS<<<cK * cD, 512, 0, stream>>>(x, xT, delta, Bs, Cs, Alog, Dsv, y);
    kE<<<288, 256, 0, stream>>>(y, lnw, lnb, out);
}

// Round 11
// 99.537 us; speedup vs baseline: 1.0511x; 1.0511x over previous
//
#include <hip/hip_runtime.h>
#include <math.h>

// SS2D: B=1, D=96, H=W=96, L=9216, K=4, N=16, R=6
constexpr int cD = 96, cL = 9216, cK = 4;
constexpr int CL = 72, NCH = 128;       // 128 chunks of 72 per sequence
constexpr long cDL = (long)cD * cL;
constexpr float LOG2E = 1.44269504088896f;

// ws float offsets (~43.6 MB)
constexpr long OFF_XT    = 0;                       // [96][9216]
constexpr long OFF_DELTA = OFF_XT    + cDL;         // [K][96][9216] d-major
constexpr long OFF_BS    = OFF_DELTA + 4L*cDL;      // [K][72][128][16] j-major
constexpr long OFF_CS    = OFF_BS    + 4L*cL*16;    // [K][72][128][16]
constexpr long OFF_Y     = OFF_CS    + 4L*cL*16;    // [K][96][9216] scan-raster
constexpr long OFF_YT    = OFF_Y     + 4L*cDL;      // [2][96][9216] Y1T,Y3T

__device__ __forceinline__ float4 a2prep(float4 v) {
    return make_float4(-LOG2E * exp2f(LOG2E * v.x), -LOG2E * exp2f(LOG2E * v.y),
                       -LOG2E * exp2f(LOG2E * v.z), -LOG2E * exp2f(LOG2E * v.w));
}
template<int C>
__device__ __forceinline__ float qperm(float v) {
    return __int_as_float(__builtin_amdgcn_mov_dpp(__float_as_int(v), C, 0xf, 0xf, true));
}

// ---- kT: xT[d][w*96+h] = x[d][h*96+w] --------------------------------------
__global__ __launch_bounds__(256) void kT(const float* __restrict__ x,
                                          float* __restrict__ xT) {
    __shared__ float t[32][33];
    const int h0 = blockIdx.x * 32, w0 = blockIdx.y * 32, d = blockIdx.z;
    const float* xd = x + (long)d * cL;
    float* xtd = xT + (long)d * cL;
    for (int o = threadIdx.x; o < 1024; o += 256) {
        int i = o >> 5, j = o & 31;
        t[i][j] = xd[(h0 + i) * 96 + w0 + j];
    }
    __syncthreads();
    for (int o = threadIdx.x; o < 1024; o += 256) {
        int i = o >> 5, j = o & 31;
        xtd[(w0 + i) * 96 + h0 + j] = t[j][i];
    }
}

// ---- kA: G = W_k @ src_k; delta[k][d][p], Bs/Cs[k][72][128][16] ------------
__global__ __launch_bounds__(256) void kA(const float* __restrict__ x,
                                          const float* __restrict__ xT,
                                          const float* __restrict__ xpw,
                                          const float* __restrict__ dtw,
                                          const float* __restrict__ dtb,
                                          float* __restrict__ delta,
                                          float* __restrict__ Bs,
                                          float* __restrict__ Cs) {
    __shared__ float xs[96][64];
    __shared__ float xdbl[38][65];
    __shared__ float dtw_l[96 * 6];
    __shared__ float dtb_l[96];
    const int p0 = blockIdx.x * 64;
    const int k  = blockIdx.y;
    const int tid = threadIdx.x;
    const float* src = (k & 1) ? xT : x;

    for (int o = tid; o < 96 * 64; o += 256) {
        int dd = o >> 6, pp = o & 63;
        xs[dd][pp] = src[(long)dd * cL + p0 + pp];
    }
    for (int o = tid; o < 96 * 6; o += 256) dtw_l[o] = dtw[k * 96 * 6 + o];
    if (tid < 96) dtb_l[tid] = dtb[k * 96 + tid];
    __syncthreads();

    const int lane = tid & 63;
    const int c0 = __builtin_amdgcn_readfirstlane((tid >> 6) * 10);
    const float* wk = xpw + (long)k * 38 * 96;
    float acc[10];
    #pragma unroll
    for (int i = 0; i < 10; ++i) acc[i] = 0.f;
    #pragma unroll 4
    for (int dd = 0; dd < 96; ++dd) {
        float xv = xs[dd][lane];
        #pragma unroll
        for (int i = 0; i < 10; ++i) {
            int c = c0 + i; c = c > 37 ? 37 : c;
            acc[i] = fmaf(xv, wk[c * 96 + dd], acc[i]);
        }
    }
    #pragma unroll
    for (int i = 0; i < 10; ++i) {
        int c = c0 + i; c = c > 37 ? 37 : c;
        xdbl[c][lane] = acc[i];
    }
    __syncthreads();

    // Bs/Cs scan-chunk-major: q = scan index, ch = q/72, j = q%72
    for (int o = tid; o < 64 * 16; o += 256) {
        int n = o & 15, pp = o >> 4;
        int P = p0 + pp;
        int q = (k < 2) ? P : (9215 - P);
        int ch = q / 72, j = q - ch * 72;
        long idx = (((long)k * 72 + j) * 128 + ch) * 16 + n;
        Bs[idx] = xdbl[6 + n][pp];
        Cs[idx] = xdbl[22 + n][pp];
    }
    for (int o = tid; o < 96 * 64; o += 256) {
        int dd = o >> 6, pp = o & 63;
        float s = dtb_l[dd];
        #pragma unroll
        for (int r = 0; r < 6; ++r) s = fmaf(xdbl[r][pp], dtw_l[dd * 6 + r], s);
        float sp = fmaxf(s, 0.f) + __logf(1.f + __expf(-fabsf(s)));
        delta[((long)(k * 96 + dd)) * cL + p0 + pp] = sp;
    }
}

// ---- kS: fused two-pass scan; y stored in scan raster (no ybuf) ------------
__global__ __launch_bounds__(512, 4) void kS(const float* __restrict__ x,
                                             const float* __restrict__ xT,
                                             const float* __restrict__ delta,
                                             const float* __restrict__ Bs,
                                             const float* __restrict__ Cs,
                                             const float* __restrict__ Alog,
                                             const float* __restrict__ Dsv,
                                             float* __restrict__ y) {
    __shared__ float lp[NCH][16];        // 8 KB (rows 0..63 reused as gpf)
    __shared__ float ls[NCH][16];        // 8 KB
    float* gpf = &lp[0][0];
    const int tid = threadIdx.x;
    const int seq = blockIdx.x;                    // k*96+d
    const int k = seq / 96, d = seq % 96, rev = k >> 1;
    const int n0 = (tid & 3) * 4, ch = tid >> 2;   // ch in [0,128)
    const int r = tid & 3;
    const int q0 = rev ? (9215 - ch * CL) : ch * CL;

    const float4 a2 = a2prep(*(const float4*)(Alog + (long)seq * 16 + n0));
    const float Dv = Dsv[seq];
    const float* dB = delta + (long)seq * cL + q0;
    const float* xB = ((k & 1) ? xT : x) + (long)d * cL + q0;
    const float* bB = Bs + (long)k * cL * 16 + (long)ch * 16 + n0;
    const float* cB = Cs + (long)k * cL * 16 + (long)ch * 16 + n0;

    // ---- pass 1: chunk summary ----
    float4 h = make_float4(0.f, 0.f, 0.f, 0.f);
    float sdl = 0.f;
#define S1(DL, XV, OFF) { \
        float4 B = *(const float4*)(bB + (OFF) * 2048); \
        float t = (DL) * (XV); sdl += (DL); \
        h.x = fmaf(exp2f((DL)*a2.x), h.x, t*B.x); \
        h.y = fmaf(exp2f((DL)*a2.y), h.y, t*B.y); \
        h.z = fmaf(exp2f((DL)*a2.z), h.z, t*B.z); \
        h.w = fmaf(exp2f((DL)*a2.w), h.w, t*B.w); }
    if (!rev) {
        #pragma unroll
        for (int g = 0; g < 18; ++g) {
            float4 d4 = *(const float4*)(dB + 4*g);
            float4 x4 = *(const float4*)(xB + 4*g);
            S1(d4.x, x4.x, 4*g)   S1(d4.y, x4.y, 4*g+1)
            S1(d4.z, x4.z, 4*g+2) S1(d4.w, x4.w, 4*g+3)
        }
    } else {
        #pragma unroll
        for (int g = 0; g < 18; ++g) {
            float4 d4 = *(const float4*)(dB - 4*g - 3);
            float4 x4 = *(const float4*)(xB - 4*g - 3);
            S1(d4.w, x4.w, 4*g)   S1(d4.z, x4.z, 4*g+1)
            S1(d4.y, x4.y, 4*g+2) S1(d4.x, x4.x, 4*g+3)
        }
    }
#undef S1
    *(float4*)&lp[ch][n0] = make_float4(exp2f(a2.x*sdl), exp2f(a2.y*sdl),
                                        exp2f(a2.z*sdl), exp2f(a2.w*sdl));
    *(float4*)&ls[ch][n0] = h;
    __syncthreads();

    // ---- scan of 128 summaries: serial-4 -> KS over 32 groups -> apply ----
    const int sn = tid & 15, sg = tid >> 4;        // sg in [0,32)
    float LPe[4], LSe[4];
    {
        float P = 1.f, S = 0.f;
        #pragma unroll
        for (int i = 0; i < 4; ++i) {
            LPe[i] = P; LSe[i] = S;
            float p = lp[sg * 4 + i][sn], s = ls[sg * 4 + i][sn];
            S = fmaf(p, S, s); P = p * P;
        }
        __syncthreads();
        gpf[tid] = P; gpf[512 + tid] = S;
    }
    __syncthreads();
    #pragma unroll
    for (int off = 1; off < 32; off <<= 1) {
        float pc = gpf[tid], sc = gpf[512 + tid];
        float pn = pc, snn = sc;
        if (sg >= off) {
            pn  = pc * gpf[tid - off * 16];
            snn = fmaf(pc, gpf[512 + tid - off * 16], sc);
        }
        __syncthreads();
        gpf[tid] = pn; gpf[512 + tid] = snn;
        __syncthreads();
    }
    const float GS = (sg == 0) ? 0.f : gpf[512 + tid - 16];
    #pragma unroll
    for (int i = 0; i < 4; ++i) ls[sg * 4 + i][sn] = fmaf(LPe[i], GS, LSe[i]);
    __syncthreads();

    // ---- pass 2: replay with exclusive init; unified scan-raster store -----
    h = *(float4*)&ls[ch][n0];
    float* yq = y + (long)seq * cL + ch * CL;      // scan-raster, ascending
    float yhold = 0.f;
#define S2(DL, XV, SI, OFF) { \
        float4 B = *(const float4*)(bB + (OFF) * 2048); \
        float4 C = *(const float4*)(cB + (OFF) * 2048); \
        float t = (DL) * (XV); \
        h.x = fmaf(exp2f((DL)*a2.x), h.x, t*B.x); \
        h.y = fmaf(exp2f((DL)*a2.y), h.y, t*B.y); \
        h.z = fmaf(exp2f((DL)*a2.z), h.z, t*B.z); \
        h.w = fmaf(exp2f((DL)*a2.w), h.w, t*B.w); \
        float pv = fmaf(h.x, C.x, fmaf(h.y, C.y, fmaf(h.z, C.z, h.w * C.w))); \
        pv += qperm<0xB1>(pv); \
        pv += qperm<0x4E>(pv); \
        if ((SI) == r) yhold = fmaf(Dv, (XV), pv); }
    if (!rev) {
        #pragma unroll
        for (int g = 0; g < 18; ++g) {
            float4 d4 = *(const float4*)(dB + 4*g);
            float4 x4 = *(const float4*)(xB + 4*g);
            S2(d4.x, x4.x, 0, 4*g)   S2(d4.y, x4.y, 1, 4*g+1)
            S2(d4.z, x4.z, 2, 4*g+2) S2(d4.w, x4.w, 3, 4*g+3)
            yq[4*g + r] = yhold;
        }
    } else {
        #pragma unroll
        for (int g = 0; g < 18; ++g) {
            float4 d4 = *(const float4*)(dB - 4*g - 3);
            float4 x4 = *(const float4*)(xB - 4*g - 3);
            S2(d4.w, x4.w, 0, 4*g)   S2(d4.z, x4.z, 1, 4*g+1)
            S2(d4.y, x4.y, 2, 4*g+2) S2(d4.x, x4.x, 3, 4*g+3)
            yq[4*g + r] = yhold;
        }
    }
#undef S2
}

// ---- kU: transpose Y1,Y3 (scan raster -> spatial raster) -------------------
__global__ __launch_bounds__(256) void kU(const float* __restrict__ Y,
                                          float* __restrict__ YT) {
    __shared__ float t[32][33];
    const int i0 = blockIdx.x * 32, j0 = blockIdx.y * 32;
    const int z = blockIdx.z;
    const int arr = z / 96, d = z % 96;              // arr 0 -> Y1, 1 -> Y3
    const float* src = Y + (1 + 2 * arr) * cDL + (long)d * cL;
    float* dst = YT + (long)arr * cDL + (long)d * cL;
    for (int o = threadIdx.x; o < 1024; o += 256) {
        int i = o >> 5, j = o & 31;
        t[i][j] = src[(i0 + i) * 96 + j0 + j];
    }
    __syncthreads();
    for (int o = threadIdx.x; o < 1024; o += 256) {
        int i = o >> 5, j = o & 31;
        dst[(j0 + i) * 96 + i0 + j] = t[j][i];
    }
}

// ---- kE: 4-dir sum + LayerNorm; Y0/Y1T direct, Y2/Y3T reversed -------------
__global__ __launch_bounds__(256) void kE(const float* __restrict__ Y,
                                          const float* __restrict__ YT,
                                          const float* __restrict__ lnw,
                                          const float* __restrict__ lnb,
                                          float* __restrict__ out) {
    __shared__ float vs[96][36];
    __shared__ float red[8][32], red2[8][32];
    __shared__ float MU[32], RS[32];
    const int tid = threadIdx.x;
    const int p0 = blockIdx.x * 32;

    for (int o = tid; o < 96 * 8; o += 256) {
        int dd = o >> 3, j = o & 7;
        const float* r0 = Y + (long)dd * cL + p0;                  // Y0 direct
        const float* r1 = YT + (long)dd * cL + p0;                 // Y1T direct
        const float* r2 = Y + 2 * cDL + (long)dd * cL;             // Y2 reversed
        const float* r3 = YT + cDL + (long)dd * cL;                // Y3T reversed
        float4 a = ((const float4*)r0)[j];
        float4 b = ((const float4*)r1)[j];
        float4 c = *(const float4*)(r2 + 9212 - p0 - 4 * j);
        float4 e = *(const float4*)(r3 + 9212 - p0 - 4 * j);
        *(float4*)&vs[dd][4 * j] = make_float4(a.x + b.x + c.w + e.w,
                                               a.y + b.y + c.z + e.z,
                                               a.z + b.z + c.y + e.y,
                                               a.w + b.w + c.x + e.x);
    }
    __syncthreads();

    const int p = tid & 31, part = tid >> 5;
    float s = 0.f, s2 = 0.f;
    for (int dd = part * 12; dd < part * 12 + 12; ++dd) {
        float v = vs[dd][p];
        s += v; s2 = fmaf(v, v, s2);
    }
    red[part][p] = s; red2[part][p] = s2;
    __syncthreads();
    if (tid < 32) {
        float S = 0.f, S2 = 0.f;
        #pragma unroll
        for (int q = 0; q < 8; ++q) { S += red[q][tid]; S2 += red2[q][tid]; }
        float m = S * (1.f / 96.f);
        MU[tid] = m;
        RS[tid] = rsqrtf(S2 * (1.f / 96.f) - m * m + 1e-5f);
    }
    __syncthreads();
    for (int o = tid; o < 32 * 96; o += 256) {
        int pl = o / 96, dd = o - pl * 96;
        out[(long)(p0 + pl) * 96 + dd] = (vs[dd][pl] - MU[pl]) * RS[pl] * lnw[dd] + lnb[dd];
    }
}

extern "C" void kernel_launch(void* const* d_in, const int* in_sizes, int n_in,
                              void* d_out, int out_size, void* d_ws, size_t ws_size,
                              hipStream_t stream) {
    const float* x    = (const float*)d_in[0];
    const float* xpw  = (const float*)d_in[1];
    const float* dtw  = (const float*)d_in[2];
    const float* dtb  = (const float*)d_in[3];
    const float* Alog = (const float*)d_in[4];
    const float* Dsv  = (const float*)d_in[5];
    const float* lnw  = (const float*)d_in[6];
    const float* lnb  = (const float*)d_in[7];
    float* ws = (float*)d_ws;

    float* xT    = ws + OFF_XT;
    float* delta = ws + OFF_DELTA;
    float* Bs    = ws + OFF_BS;
    float* Cs    = ws + OFF_CS;
    float* y     = ws + OFF_Y;
    float* yT    = ws + OFF_YT;
    float* out   = (float*)d_out;

    kT<<<dim3(3, 3, 96), 256, 0, stream>>>(x, xT);
    kA<<<dim3(144, 4), 256, 0, stream>>>(x, xT, xpw, dtw, dtb, delta, Bs, Cs);
    kS<<<cK * cD, 512, 0, stream>>>(x, xT, delta, Bs, Cs, Alog, Dsv, y);
    kU<<<dim3(3, 3, 192), 256, 0, stream>>>(y, yT);
    kE<<<288, 256, 0, stream>>>(y, yT, lnw, lnb, out);
}